// Round 2
// baseline (491.793 us; speedup 1.0000x reference)
//
#include <hip/hip_runtime.h>

#define N_NODES 100000
#define N_EDGES 1250000
#define D 64
#define PAD 68   // LDS row pad: keeps float4 alignment (68%4==0), 8-way write conflict only during staging

typedef unsigned int u32;

// ---------------------------------------------------------------------------
// CSR build step 1: in-degree count. 1.25M int atomics on a 400KB array.
// ---------------------------------------------------------------------------
__global__ void __launch_bounds__(256) k_count(const int* __restrict__ ei, u32* __restrict__ cnt) {
    int e = blockIdx.x * 256 + threadIdx.x;
    if (e >= N_EDGES) return;
    atomicAdd(&cnt[ei[N_EDGES + e]], 1u);
}

// ---------------------------------------------------------------------------
// CSR build step 2: exclusive prefix sum over 100K counts, single block.
// Each of 1024 threads owns a 98-element chunk; Kogge-Stone scan of partials.
// Writes offs[] and a second copy cursor[] for the fill kernel to bump.
// ---------------------------------------------------------------------------
__global__ void __launch_bounds__(1024) k_scan(const u32* __restrict__ cnt,
                                               u32* __restrict__ offs,
                                               u32* __restrict__ cursor) {
    __shared__ u32 ps[1024];
    int t = threadIdx.x;
    const int CH = 98;                 // 1024*98 = 100352 >= 100000
    int beg = t * CH;
    int end = min(beg + CH, N_NODES);
    u32 s = 0;
    for (int i = beg; i < end; ++i) s += cnt[i];
    ps[t] = s;
    __syncthreads();
    for (int off = 1; off < 1024; off <<= 1) {
        u32 v = (t >= off) ? ps[t - off] : 0u;
        __syncthreads();
        ps[t] += v;
        __syncthreads();
    }
    u32 run = (t == 0) ? 0u : ps[t - 1];
    for (int i = beg; i < end; ++i) {
        offs[i] = run;
        cursor[i] = run;
        run += cnt[i];
    }
    if (t == 1023) offs[N_NODES] = run;  // run == total (this thread's chunk is empty)
}

// ---------------------------------------------------------------------------
// CSR build step 3: fill adjacency (unordered within a segment - fp add order
// is arbitrary anyway). Adjacent slots of one dst share cache lines.
// ---------------------------------------------------------------------------
__global__ void __launch_bounds__(256) k_fill(const int* __restrict__ ei,
                                              u32* __restrict__ cursor,
                                              u32* __restrict__ csr) {
    int e = blockIdx.x * 256 + threadIdx.x;
    if (e >= N_EDGES) return;
    int dst = ei[N_EDGES + e];
    u32 slot = atomicAdd(&cursor[dst], 1u);
    csr[slot] = (u32)ei[e];
}

// ---------------------------------------------------------------------------
// Gather: one wave per node, lane = feature. Sums neighbor rows (256B
// coalesced reads, served by L2/L3 since x = 25.6MB << 256MB L3), scales by
// 1/max(deg,1), writes mean-agg to d_out.
// ---------------------------------------------------------------------------
__global__ void __launch_bounds__(256) k_gather(const float* __restrict__ x,
                                                const u32* __restrict__ offs,
                                                const u32* __restrict__ csr,
                                                float* __restrict__ agg) {
    int tid = blockIdx.x * 256 + threadIdx.x;
    int node = tid >> 6;
    int d = tid & 63;
    if (node >= N_NODES) return;
    u32 o0 = offs[node], o1 = offs[node + 1];
    float s = 0.f;
    u32 j = o0;
    for (; j + 1 < o1; j += 2) {           // 2-way unroll: two loads in flight
        u32 s0 = csr[j], s1 = csr[j + 1];
        float v0 = x[(size_t)s0 * D + d];
        float v1 = x[(size_t)s1 * D + d];
        s += v0;
        s += v1;
    }
    if (j < o1) s += x[(size_t)csr[j] * D + d];
    float inv = 1.0f / (float)max(o1 - o0, 1u);
    agg[(size_t)node * D + d] = s * inv;
}

// ---------------------------------------------------------------------------
// Transform GEMM: C[100K x 64] = [agg | x] (100K x 128) @ [WnT; WsT] (128x64) + b.
// Block = 64 nodes, 256 threads, 4x4 micro-tile per thread.
// A and W staged transposed to [k][n]/[k][d] so the inner loop is
// 2x ds_read_b128 per 16 FMAs. In-place on d_out (each block only touches
// its own 64 rows; tile is fully staged to LDS before any store).
// ---------------------------------------------------------------------------
__global__ void __launch_bounds__(256) k_gemm(const float* __restrict__ x,
                                              const float* __restrict__ wn,
                                              const float* __restrict__ wsf,
                                              const float* __restrict__ b,
                                              float* __restrict__ io) {
    __shared__ float At[128 * PAD];   // [k][node], k: 0..63 agg, 64..127 x
    __shared__ float Wt[128 * PAD];   // [k][dout]
    int tid = threadIdx.x;
    int base = blockIdx.x * 64;

    for (int i = tid; i < 4096; i += 256) {
        int r = i >> 6, k = i & 63;        // r: node-in-tile / weight out-row; k coalesced on lanes
        int node = base + r;
        float va = 0.f, vx = 0.f;
        if (node < N_NODES) {
            va = io[(size_t)node * D + k];
            vx = x[(size_t)node * D + k];
        }
        At[k * PAD + r] = va;
        At[(64 + k) * PAD + r] = vx;
        Wt[k * PAD + r] = wn[i];           // Wt[k][d] = wn[d][k]
        Wt[(64 + k) * PAD + r] = wsf[i];
    }
    __syncthreads();

    int tn = tid >> 4, td = tid & 15;
    int n0 = tn * 4, d0 = td * 4;
    float4 bv4 = *(const float4*)&b[d0];
    float bv[4] = {bv4.x, bv4.y, bv4.z, bv4.w};
    float acc[4][4];
#pragma unroll
    for (int i = 0; i < 4; ++i)
#pragma unroll
        for (int j = 0; j < 4; ++j) acc[i][j] = bv[j];

#pragma unroll 8
    for (int k = 0; k < 128; ++k) {
        float4 a4 = *(const float4*)&At[k * PAD + n0];
        float4 w4 = *(const float4*)&Wt[k * PAD + d0];
        float a[4] = {a4.x, a4.y, a4.z, a4.w};
        float w[4] = {w4.x, w4.y, w4.z, w4.w};
#pragma unroll
        for (int i = 0; i < 4; ++i)
#pragma unroll
            for (int j = 0; j < 4; ++j) acc[i][j] += a[i] * w[j];
    }

#pragma unroll
    for (int i = 0; i < 4; ++i) {
        int node = base + n0 + i;
        if (node < N_NODES) {
            float4 o = make_float4(acc[i][0], acc[i][1], acc[i][2], acc[i][3]);
            *(float4*)&io[(size_t)node * D + d0] = o;
        }
    }
}

extern "C" void kernel_launch(void* const* d_in, const int* in_sizes, int n_in,
                              void* d_out, int out_size, void* d_ws, size_t ws_size,
                              hipStream_t stream) {
    const float* x = (const float*)d_in[0];
    const int* ei = (const int*)d_in[1];
    const float* wn = (const float*)d_in[2];
    const float* wsf = (const float*)d_in[3];
    const float* b = (const float*)d_in[4];
    float* out = (float*)d_out;

    // Workspace layout (all u32, ~6.2 MB total)
    u32* cnt    = (u32*)d_ws;            // [100000]
    u32* offs   = cnt + N_NODES;         // [100001]
    u32* cursor = offs + N_NODES + 4;    // [100000]
    u32* csr    = cursor + N_NODES;      // [1250000]

    hipMemsetAsync(cnt, 0, (size_t)N_NODES * sizeof(u32), stream);

    int egrid = (N_EDGES + 255) / 256;
    k_count<<<egrid, 256, 0, stream>>>(ei, cnt);
    k_scan<<<1, 1024, 0, stream>>>(cnt, offs, cursor);
    k_fill<<<egrid, 256, 0, stream>>>(ei, cursor, csr);
    k_gather<<<(N_NODES * 64) / 256, 256, 0, stream>>>(x, offs, csr, out);
    k_gemm<<<(N_NODES + 63) / 64, 256, 0, stream>>>(x, wn, wsf, b, out);
}

// Round 3
// 265.895 us; speedup vs baseline: 1.8496x; 1.8496x over previous
//
#include <hip/hip_runtime.h>

#define N_NODES 100000
#define N_EDGES 1250000
#define D 64
#define PAD 68       // LDS row pad for GEMM staging
#define NBLK 391     // ceil(100000/256)

typedef unsigned int u32;

// ---------------------------------------------------------------------------
// CSR step 1: in-degree count. 1.25M int atomics on a 400KB array.
// ---------------------------------------------------------------------------
__global__ void __launch_bounds__(256) k_count(const int* __restrict__ ei, u32* __restrict__ cnt) {
    int e = blockIdx.x * 256 + threadIdx.x;
    if (e >= N_EDGES) return;
    atomicAdd(&cnt[ei[N_EDGES + e]], 1u);
}

// ---------------------------------------------------------------------------
// CSR step 2a: per-block inclusive scan (256 elems/block).
// offs[i] <- inclusive scan within block; partials[blk] <- block total.
// ---------------------------------------------------------------------------
__global__ void __launch_bounds__(256) k_scan_blk(const u32* __restrict__ cnt,
                                                  u32* __restrict__ offs,
                                                  u32* __restrict__ partials) {
    __shared__ u32 wtot[4];
    int t = threadIdx.x;
    int i = blockIdx.x * 256 + t;
    int lane = t & 63, wave = t >> 6;
    u32 v = (i < N_NODES) ? cnt[i] : 0u;
    u32 s = v;
#pragma unroll
    for (int off = 1; off < 64; off <<= 1) {
        u32 n = __shfl_up(s, off, 64);
        if (lane >= off) s += n;
    }
    if (lane == 63) wtot[wave] = s;
    __syncthreads();
    u32 add = 0;
    for (int w = 0; w < wave; ++w) add += wtot[w];
    s += add;
    if (i < N_NODES) offs[i] = s;              // inclusive, block-local
    if (t == 0) partials[blockIdx.x] = wtot[0] + wtot[1] + wtot[2] + wtot[3];
}

// ---------------------------------------------------------------------------
// CSR step 2b: scan 391 block totals (single tiny block), exclusive in place.
// Also writes offs[N_NODES] = total edge count.
// ---------------------------------------------------------------------------
__global__ void __launch_bounds__(512) k_scan_part(u32* __restrict__ partials,
                                                   u32* __restrict__ offs) {
    __shared__ u32 ps[512];
    int t = threadIdx.x;
    ps[t] = (t < NBLK) ? partials[t] : 0u;
    __syncthreads();
    for (int off = 1; off < 512; off <<= 1) {
        u32 v = (t >= off) ? ps[t - off] : 0u;
        __syncthreads();
        ps[t] += v;
        __syncthreads();
    }
    if (t < NBLK) partials[t] = (t == 0) ? 0u : ps[t - 1];   // exclusive
    if (t == 0) offs[N_NODES] = ps[NBLK - 1];
}

// ---------------------------------------------------------------------------
// CSR step 2c: add block prefix, convert inclusive->exclusive, fill cursor.
// ---------------------------------------------------------------------------
__global__ void __launch_bounds__(256) k_scan_fix(const u32* __restrict__ cnt,
                                                  const u32* __restrict__ partials,
                                                  u32* __restrict__ offs,
                                                  u32* __restrict__ cursor) {
    int i = blockIdx.x * 256 + threadIdx.x;
    if (i >= N_NODES) return;
    u32 excl = offs[i] + partials[blockIdx.x] - cnt[i];
    offs[i] = excl;
    cursor[i] = excl;
}

// ---------------------------------------------------------------------------
// CSR step 3: fill adjacency (unordered within segment - fp order arbitrary).
// ---------------------------------------------------------------------------
__global__ void __launch_bounds__(256) k_fill(const int* __restrict__ ei,
                                              u32* __restrict__ cursor,
                                              u32* __restrict__ csr) {
    int e = blockIdx.x * 256 + threadIdx.x;
    if (e >= N_EDGES) return;
    int dst = ei[N_EDGES + e];
    u32 slot = atomicAdd(&cursor[dst], 1u);
    csr[slot] = (u32)ei[e];
}

// ---------------------------------------------------------------------------
// Gather: one wave per node, lane = feature. x (25.6MB) is L2/L3-resident.
// ---------------------------------------------------------------------------
__global__ void __launch_bounds__(256) k_gather(const float* __restrict__ x,
                                                const u32* __restrict__ offs,
                                                const u32* __restrict__ csr,
                                                float* __restrict__ agg) {
    int tid = blockIdx.x * 256 + threadIdx.x;
    int node = tid >> 6;
    int d = tid & 63;
    if (node >= N_NODES) return;
    u32 o0 = offs[node], o1 = offs[node + 1];
    float s = 0.f;
    u32 j = o0;
    for (; j + 3 < o1; j += 4) {               // 4 loads in flight
        u32 s0 = csr[j], s1 = csr[j + 1], s2 = csr[j + 2], s3 = csr[j + 3];
        float v0 = x[(size_t)s0 * D + d];
        float v1 = x[(size_t)s1 * D + d];
        float v2 = x[(size_t)s2 * D + d];
        float v3 = x[(size_t)s3 * D + d];
        s += v0; s += v1; s += v2; s += v3;
    }
    for (; j < o1; ++j) s += x[(size_t)csr[j] * D + d];
    float inv = 1.0f / (float)max(o1 - o0, 1u);
    agg[(size_t)node * D + d] = s * inv;
}

// ---------------------------------------------------------------------------
// Transform GEMM: C[100K x 64] = [agg | x] (100K x 128) @ [WnT; WsT] + b.
// Block = 64 nodes, 256 threads, 4x4 micro-tile. In-place on d_out.
// ---------------------------------------------------------------------------
__global__ void __launch_bounds__(256) k_gemm(const float* __restrict__ x,
                                              const float* __restrict__ wn,
                                              const float* __restrict__ wsf,
                                              const float* __restrict__ b,
                                              float* __restrict__ io) {
    __shared__ float At[128 * PAD];   // [k][node]
    __shared__ float Wt[128 * PAD];   // [k][dout]
    int tid = threadIdx.x;
    int base = blockIdx.x * 64;

    for (int i = tid; i < 4096; i += 256) {
        int r = i >> 6, k = i & 63;
        int node = base + r;
        float va = 0.f, vx = 0.f;
        if (node < N_NODES) {
            va = io[(size_t)node * D + k];
            vx = x[(size_t)node * D + k];
        }
        At[k * PAD + r] = va;
        At[(64 + k) * PAD + r] = vx;
        Wt[k * PAD + r] = wn[i];
        Wt[(64 + k) * PAD + r] = wsf[i];
    }
    __syncthreads();

    int tn = tid >> 4, td = tid & 15;
    int n0 = tn * 4, d0 = td * 4;
    float4 bv4 = *(const float4*)&b[d0];
    float bv[4] = {bv4.x, bv4.y, bv4.z, bv4.w};
    float acc[4][4];
#pragma unroll
    for (int i = 0; i < 4; ++i)
#pragma unroll
        for (int j = 0; j < 4; ++j) acc[i][j] = bv[j];

#pragma unroll 8
    for (int k = 0; k < 128; ++k) {
        float4 a4 = *(const float4*)&At[k * PAD + n0];
        float4 w4 = *(const float4*)&Wt[k * PAD + d0];
        float a[4] = {a4.x, a4.y, a4.z, a4.w};
        float w[4] = {w4.x, w4.y, w4.z, w4.w};
#pragma unroll
        for (int i = 0; i < 4; ++i)
#pragma unroll
            for (int j = 0; j < 4; ++j) acc[i][j] += a[i] * w[j];
    }

#pragma unroll
    for (int i = 0; i < 4; ++i) {
        int node = base + n0 + i;
        if (node < N_NODES) {
            float4 o = make_float4(acc[i][0], acc[i][1], acc[i][2], acc[i][3]);
            *(float4*)&io[(size_t)node * D + d0] = o;
        }
    }
}

extern "C" void kernel_launch(void* const* d_in, const int* in_sizes, int n_in,
                              void* d_out, int out_size, void* d_ws, size_t ws_size,
                              hipStream_t stream) {
    const float* x = (const float*)d_in[0];
    const int* ei = (const int*)d_in[1];
    const float* wn = (const float*)d_in[2];
    const float* wsf = (const float*)d_in[3];
    const float* b = (const float*)d_in[4];
    float* out = (float*)d_out;

    // Workspace layout (u32), ~6.2 MB
    u32* cnt      = (u32*)d_ws;              // [100000]
    u32* offs     = cnt + N_NODES;           // [100001 (+3 pad)]
    u32* cursor   = offs + N_NODES + 4;      // [100000]
    u32* csr      = cursor + N_NODES;        // [1250000]
    u32* partials = csr + N_EDGES;           // [512]

    hipMemsetAsync(cnt, 0, (size_t)N_NODES * sizeof(u32), stream);

    int egrid = (N_EDGES + 255) / 256;
    k_count<<<egrid, 256, 0, stream>>>(ei, cnt);
    k_scan_blk<<<NBLK, 256, 0, stream>>>(cnt, offs, partials);
    k_scan_part<<<1, 512, 0, stream>>>(partials, offs);
    k_scan_fix<<<NBLK, 256, 0, stream>>>(cnt, partials, offs, cursor);
    k_fill<<<egrid, 256, 0, stream>>>(ei, cursor, csr);
    k_gather<<<(N_NODES * 64) / 256, 256, 0, stream>>>(x, offs, csr, out);
    k_gemm<<<(N_NODES + 63) / 64, 256, 0, stream>>>(x, wn, wsf, b, out);
}